// Round 1
// baseline (159.656 us; speedup 1.0000x reference)
//
#include <hip/hip_runtime.h>

#define IMG_H 512
#define IMG_W 512
#define NPLANES 48                  // 16 batch * 3 channels
#define PLANE_SZ (IMG_H * IMG_W)
#define N_ELEM (NPLANES * PLANE_SZ) // 12,582,912

#define TILE_W 48
#define TILE_H 32
#define GX 11                       // ceil(512/48)
#define GY 16                       // 512/32
#define NBLOCKS (GX * GY * NPLANES) // 8448

#define SSIM_C1 1e-4f
#define SSIM_C2 9e-4f

// Tile kernel: separable 11x11 Gaussian convs (vertical from global in
// registers, horizontal through LDS), SSIM map, per-block partial sum.
__global__ __launch_bounds__(256) void ssim_tile_kernel(
    const float* __restrict__ img1, const float* __restrict__ img2,
    double* __restrict__ partials)
{
    __shared__ float4 vs4[TILE_H][65];  // (mu1v, mu2v, xxv, yyv) pitch 65: <=2-way banks
    __shared__ float  vs1[TILE_H][65];  // xyv
    __shared__ double wred[4];

    const int tid  = threadIdx.x;
    const int lane = tid & 63;
    const int wv   = tid >> 6;

    // Gaussian window (ws=11, sigma=1.5) in registers. __expf err ~1e-6 rel,
    // far inside the 2.6e-4 threshold.
    float gwr[11];
    {
        float s = 0.f;
        #pragma unroll
        for (int i = 0; i < 11; ++i) {
            const float d = (float)(i - 5);
            gwr[i] = __expf(d * d * (-1.0f / 4.5f));
            s += gwr[i];
        }
        const float inv = 1.0f / s;
        #pragma unroll
        for (int i = 0; i < 11; ++i) gwr[i] *= inv;
    }

    const int plane = blockIdx.z;
    const int ox = blockIdx.x * TILE_W;
    const int oy = blockIdx.y * TILE_H;
    const float* p1 = img1 + (size_t)plane * PLANE_SZ;
    const float* p2 = img2 + (size_t)plane * PLANE_SZ;

    // ---- vertical pass: wave wv computes vsums for output rows
    // [oy + wv*8, oy + wv*8 + 8), halo columns ox-5 .. ox+58 (lane = col).
    {
        const int r0   = wv * 8;
        const int gcol = ox + lane - 5;
        const bool colok = (gcol >= 0) && (gcol < IMG_W);
        float ax[8], ay[8], axx[8], ayy[8], axy[8];
        #pragma unroll
        for (int o = 0; o < 8; ++o) { ax[o]=0.f; ay[o]=0.f; axx[o]=0.f; ayy[o]=0.f; axy[o]=0.f; }
        #pragma unroll
        for (int i = 0; i < 18; ++i) {     // input rows r0-5 .. r0+12
            const int gr = oy + r0 + i - 5;
            float x = 0.f, y = 0.f;
            if (colok && gr >= 0 && gr < IMG_H) {
                const int off = gr * IMG_W + gcol;
                x = p1[off];
                y = p2[off];
            }
            const float xx = x * x, yy = y * y, xy = x * y;
            #pragma unroll
            for (int o = 0; o < 8; ++o) {
                const int d = i - o;       // tap index into gwr
                if (d >= 0 && d <= 10) {
                    const float w = gwr[d];
                    ax[o]  = fmaf(w, x,  ax[o]);
                    ay[o]  = fmaf(w, y,  ay[o]);
                    axx[o] = fmaf(w, xx, axx[o]);
                    ayy[o] = fmaf(w, yy, ayy[o]);
                    axy[o] = fmaf(w, xy, axy[o]);
                }
            }
        }
        #pragma unroll
        for (int o = 0; o < 8; ++o) {
            vs4[r0 + o][lane] = make_float4(ax[o], ay[o], axx[o], ayy[o]);
            vs1[r0 + o][lane] = axy[o];
        }
    }
    __syncthreads();

    // ---- horizontal pass + SSIM: each thread -> 1 row x 6 consecutive cols
    float lsum = 0.f;
    {
        const int r  = tid >> 3;         // 0..31
        const int c0 = (tid & 7) * 6;    // 0,6,...,42
        float m1[6], m2[6], mxx[6], myy[6], mxy[6];
        #pragma unroll
        for (int j = 0; j < 6; ++j) { m1[j]=0.f; m2[j]=0.f; mxx[j]=0.f; myy[j]=0.f; mxy[j]=0.f; }
        #pragma unroll
        for (int t = 0; t < 16; ++t) {   // vsum local cols c0 .. c0+15
            const float4 v4 = vs4[r][c0 + t];
            const float  v1 = vs1[r][c0 + t];
            #pragma unroll
            for (int j = 0; j < 6; ++j) {
                const int d = t - j;
                if (d >= 0 && d <= 10) {
                    const float w = gwr[d];
                    m1[j]  = fmaf(w, v4.x, m1[j]);
                    m2[j]  = fmaf(w, v4.y, m2[j]);
                    mxx[j] = fmaf(w, v4.z, mxx[j]);
                    myy[j] = fmaf(w, v4.w, myy[j]);
                    mxy[j] = fmaf(w, v1,  mxy[j]);
                }
            }
        }
        #pragma unroll
        for (int j = 0; j < 6; ++j) {
            if (ox + c0 + j < IMG_W) {   // clip partial right-edge tile
                const float mu1 = m1[j], mu2 = m2[j];
                const float mu1s = mu1 * mu1, mu2s = mu2 * mu2, m12 = mu1 * mu2;
                const float s1  = mxx[j] - mu1s;
                const float s2  = myy[j] - mu2s;
                const float s12 = mxy[j] - m12;
                const float num = (2.f * m12 + SSIM_C1) * (2.f * s12 + SSIM_C2);
                const float den = (mu1s + mu2s + SSIM_C1) * (s1 + s2 + SSIM_C2);
                lsum += num / den;
            }
        }
    }

    // ---- block reduction -> one double partial per block
    double dsum = (double)lsum;
    #pragma unroll
    for (int off = 32; off > 0; off >>= 1)
        dsum += __shfl_down(dsum, off, 64);
    if (lane == 0) wred[wv] = dsum;
    __syncthreads();
    if (tid == 0) {
        const int bid = blockIdx.x + GX * (blockIdx.y + GY * blockIdx.z);
        partials[bid] = wred[0] + wred[1] + wred[2] + wred[3];
    }
}

__global__ __launch_bounds__(256) void ssim_finalize_kernel(
    const double* __restrict__ partials, float* __restrict__ out)
{
    __shared__ double wred[4];
    const int tid  = threadIdx.x;
    const int lane = tid & 63;
    const int wv   = tid >> 6;
    double s = 0.0;
    for (int i = tid; i < NBLOCKS; i += 256) s += partials[i];
    #pragma unroll
    for (int off = 32; off > 0; off >>= 1)
        s += __shfl_down(s, off, 64);
    if (lane == 0) wred[wv] = s;
    __syncthreads();
    if (tid == 0)
        out[0] = (float)((wred[0] + wred[1] + wred[2] + wred[3]) / (double)N_ELEM);
}

extern "C" void kernel_launch(void* const* d_in, const int* in_sizes, int n_in,
                              void* d_out, int out_size, void* d_ws, size_t ws_size,
                              hipStream_t stream)
{
    const float* img1 = (const float*)d_in[0];
    const float* img2 = (const float*)d_in[1];
    double* partials  = (double*)d_ws;          // 8448 * 8B = 67.6 KB scratch
    float* out        = (float*)d_out;

    dim3 grid(GX, GY, NPLANES);
    ssim_tile_kernel<<<grid, dim3(256), 0, stream>>>(img1, img2, partials);
    ssim_finalize_kernel<<<1, dim3(256), 0, stream>>>(partials, out);
}